// Round 16
// baseline (124.373 us; speedup 1.0000x reference)
//
#include <hip/hip_runtime.h>
#include <stdint.h>

#define B_ 64
#define P_ 32768
#define O_ 16
#define BP_CHUNK 1024                  // priors per block in best_prior_kernel
#define MCHUNK 4                       // sequential 256-pair chunks per match block
#define MATCH_BLOCKS (P_ / (512 * MCHUNK) * B_)   // 1024

constexpr float OVERLAP_THRESH = 0.5f;
constexpr int   NEG_POS_RATIO  = 3;
constexpr float VAR0 = 0.1f;
constexpr float VAR1 = 0.2f;

__device__ __forceinline__ unsigned long long umax64(unsigned long long a,
                                                     unsigned long long b) {
    return a > b ? a : b;
}

// ---------------------------------------------------------------------------
// Kernel 1: best prior per (b,o) = argmax_p IoU(truth o, prior p).
// Unchanged (R8-proven, ~7us).
// ---------------------------------------------------------------------------
__global__ __launch_bounds__(256)
void best_prior_kernel(const float* __restrict__ priors,
                       const float* __restrict__ targets,
                       unsigned long long* __restrict__ bp_pack) {
    int b   = blockIdx.y;
    int tid = threadIdx.x;
    int g   = tid >> 4;
    int o   = tid & 15;

    const float* t = targets + ((size_t)b * O_ + o) * 5;
    float tx0 = t[0], ty0 = t[1], tx1 = t[2], ty1 = t[3];
    float ta  = (tx1 - tx0) * (ty1 - ty0);

    int pbase = blockIdx.x * BP_CHUNK + g;
    float bin_ = 0.f, bun_ = 1.f;
    int   bp_  = pbase;

    #pragma unroll 4
    for (int j = 0; j < BP_CHUNK / 16; ++j) {
        int p = pbase + j * 16;
        float4 pr = ((const float4*)priors)[p];
        float px0 = pr.x - pr.z * 0.5f, py0 = pr.y - pr.w * 0.5f;
        float px1 = pr.x + pr.z * 0.5f, py1 = pr.y + pr.w * 0.5f;
        float pa  = (px1 - px0) * (py1 - py0);
        float w = fmaxf(fminf(tx1, px1) - fmaxf(tx0, px0), 0.f);
        float h = fmaxf(fminf(ty1, py1) - fmaxf(ty0, py0), 0.f);
        float in_ = w * h;
        float un_ = ta + pa - in_;
        bool gt = in_ * bun_ > bin_ * un_;
        bin_ = gt ? in_ : bin_;
        bun_ = gt ? un_ : bun_;
        bp_  = gt ? p   : bp_;
    }

    float iou = bin_ / bun_;
    unsigned long long pack =
        ((unsigned long long)__float_as_uint(iou) << 32) | (unsigned)(~bp_);

    pack = umax64(pack, __shfl_xor(pack, 16, 64));
    pack = umax64(pack, __shfl_xor(pack, 32, 64));

    __shared__ unsigned long long sw[4][16];
    int lane = tid & 63, wid = tid >> 6;
    if (lane < 16) sw[wid][lane] = pack;
    __syncthreads();
    if (tid < 16) {
        unsigned long long m = umax64(umax64(sw[0][tid], sw[1][tid]),
                                      umax64(sw[2][tid], sw[3][tid]));
        atomicMax(&bp_pack[(size_t)b * O_ + tid], m);
    }
}

// ---------------------------------------------------------------------------
// Kernel 2: match — EXACT R12 body (best measured: 42us, VGPR 80).
// No unroll pragma: compiler's own full-unroll/hoist of MCHUNK=4 is the
// measured optimum of the {prefetch-depth x occupancy} space.
// ---------------------------------------------------------------------------
__device__ __forceinline__ float sl1(float d) {
    float ad = fabsf(d);
    return (ad < 1.f) ? 0.5f * d * d : ad - 0.5f;
}

__global__ __launch_bounds__(256)
void match_kernel(const float* __restrict__ loc_data,
                  const float* __restrict__ conf_data,
                  const float* __restrict__ priors,
                  const float* __restrict__ targets,
                  const unsigned* __restrict__ bp_lo,   // bp_pack viewed as u32
                  float* __restrict__ rank,
                  int* __restrict__ num_pos,
                  float2* __restrict__ blk_part) {
    int b    = blockIdx.y;
    int tid  = threadIdx.x;

    __shared__ float4 s_box[O_];    // x0,y0,x1,y1
    __shared__ float2 s_meta[O_];   // (area, bp-as-int-bits)
    if (tid < O_) {
        const float* t = targets + ((size_t)b * O_ + tid) * 5;
        float x0 = t[0], y0 = t[1], x1 = t[2], y1 = t[3];
        s_box[tid]  = make_float4(x0, y0, x1, y1);
        int bp = (int)~bp_lo[((size_t)b * O_ + tid) * 2];   // low dword (LE)
        s_meta[tid] = make_float2((x1 - x0) * (y1 - y0), __int_as_float(bp));
    }
    __syncthreads();

    float ll = 0.f, ces = 0.f;
    int   pc = 0;

    for (int c = 0; c < MCHUNK; ++c) {
        int pair = blockIdx.x * (256 * MCHUNK) + c * 256 + tid;
        int p0   = pair * 2;

        float4 prA = ((const float4*)priors)[p0];
        float4 prB = ((const float4*)priors)[p0 + 1];
        float4 cd  = ((const float4*)conf_data)[(size_t)b * (P_ / 2) + pair];

        float ax0 = prA.x - prA.z * 0.5f, ay0 = prA.y - prA.w * 0.5f;
        float ax1 = prA.x + prA.z * 0.5f, ay1 = prA.y + prA.w * 0.5f;
        float bx0 = prB.x - prB.z * 0.5f, by0 = prB.y - prB.w * 0.5f;
        float bx1 = prB.x + prB.z * 0.5f, by1 = prB.y + prB.w * 0.5f;
        float aA = (ax1 - ax0) * (ay1 - ay0);
        float aB = (bx1 - bx0) * (by1 - by0);

        float ibA = 0.f, ubA = 1.f, ibB = 0.f, ubB = 1.f;
        int miA = 0, miB = 0, fiA = -1, fiB = -1;

        #pragma unroll
        for (int o = 0; o < O_; ++o) {
            float4 tb4 = s_box[o];
            float2 mt  = s_meta[o];
            float tx0 = tb4.x, ty0 = tb4.y, tx1 = tb4.z, ty1 = tb4.w;
            float ta  = mt.x;
            int   bp  = __float_as_int(mt.y);

            float wA  = fmaxf(fminf(tx1, ax1) - fmaxf(tx0, ax0), 0.f);
            float hA  = fmaxf(fminf(ty1, ay1) - fmaxf(ty0, ay0), 0.f);
            float inA = wA * hA;
            float unA = ta + aA - inA;
            bool  gA  = inA * ubA > ibA * unA;   // strict: first index wins ties
            ibA = gA ? inA : ibA;  ubA = gA ? unA : ubA;  miA = gA ? o : miA;
            if (bp == p0) fiA = o;               // last o wins (matches reference)

            float wB  = fmaxf(fminf(tx1, bx1) - fmaxf(tx0, bx0), 0.f);
            float hB  = fmaxf(fminf(ty1, by1) - fmaxf(ty0, by0), 0.f);
            float inB = wB * hB;
            float unB = ta + aB - inB;
            bool  gB  = inB * ubB > ibB * unB;
            ibB = gB ? inB : ibB;  ubB = gB ? unB : ubB;  miB = gB ? o : miB;
            if (bp == p0 + 1) fiB = o;
        }

        bool posA = (fiA >= 0) || (2.f * ibA >= ubA);
        bool posB = (fiB >= 0) || (2.f * ibB >= ubB);

        float mA  = fmaxf(cd.x, cd.y);
        float ceA = mA + __logf(1.f + __expf(-fabsf(cd.x - cd.y))) - (posA ? cd.y : cd.x);
        float mB  = fmaxf(cd.z, cd.w);
        float ceB = mB + __logf(1.f + __expf(-fabsf(cd.z - cd.w))) - (posB ? cd.w : cd.z);

        float2 rk;
        rk.x = posA ? 0.f : ceA;
        rk.y = posB ? 0.f : ceB;
        *(float2*)(rank + (size_t)b * P_ + p0) = rk;

        if (posA) {
            int mi = (fiA >= 0) ? fiA : miA;
            float4 tb4 = s_box[mi];
            float pz = ax1 - ax0, pw = ay1 - ay0;
            float cx = (ax0 + ax1) * 0.5f, cy = (ay0 + ay1) * 0.5f;
            float gcx = __fdividef((tb4.x + tb4.z) * 0.5f - cx, VAR0 * pz);
            float gcy = __fdividef((tb4.y + tb4.w) * 0.5f - cy, VAR0 * pw);
            float gw  = __logf(__fdividef(tb4.z - tb4.x, pz)) * (1.f / VAR1);
            float gh  = __logf(__fdividef(tb4.w - tb4.y, pw)) * (1.f / VAR1);
            float4 ld = ((const float4*)loc_data)[(size_t)b * P_ + p0];
            ll  += sl1(ld.x - gcx) + sl1(ld.y - gcy) + sl1(ld.z - gw) + sl1(ld.w - gh);
            ces += ceA;
            pc  += 1;
        }
        if (posB) {
            int mi = (fiB >= 0) ? fiB : miB;
            float4 tb4 = s_box[mi];
            float pz = bx1 - bx0, pw = by1 - by0;
            float cx = (bx0 + bx1) * 0.5f, cy = (by0 + by1) * 0.5f;
            float gcx = __fdividef((tb4.x + tb4.z) * 0.5f - cx, VAR0 * pz);
            float gcy = __fdividef((tb4.y + tb4.w) * 0.5f - cy, VAR0 * pw);
            float gw  = __logf(__fdividef(tb4.z - tb4.x, pz)) * (1.f / VAR1);
            float gh  = __logf(__fdividef(tb4.w - tb4.y, pw)) * (1.f / VAR1);
            float4 ld = ((const float4*)loc_data)[(size_t)b * P_ + p0 + 1];
            ll  += sl1(ld.x - gcx) + sl1(ld.y - gcy) + sl1(ld.z - gw) + sl1(ld.w - gh);
            ces += ceB;
            pc  += 1;
        }
    }

    for (int off = 32; off; off >>= 1) {
        ll  += __shfl_down(ll, off, 64);
        ces += __shfl_down(ces, off, 64);
        pc  += __shfl_down(pc, off, 64);
    }
    __shared__ float sll[4], sce[4];
    __shared__ int   spc[4];
    int wid = tid >> 6;
    if ((tid & 63) == 0) { sll[wid] = ll; sce[wid] = ces; spc[wid] = pc; }
    __syncthreads();
    if (tid == 0) {
        int tp = spc[0] + spc[1] + spc[2] + spc[3];
        float tl = sll[0] + sll[1] + sll[2] + sll[3];
        float tc = sce[0] + sce[1] + sce[2] + sce[3];
        blk_part[blockIdx.y * gridDim.x + blockIdx.x] = make_float2(tl, tc);
        if (tp) atomicAdd(&num_pos[b], tp);
    }
}

// ---------------------------------------------------------------------------
// Kernel 3: per batch, exact top-k sum via COUNT+SUM radix select.
// Each level histograms count AND f32 sum per bin (ds_add_f32); the dual
// suffix-scan yields the exact sum of fully-included bins per level, so
// levels 1-2 only touch the ~16 keys inside the selected bin and the final
// full compare/sum pass is eliminated. total = sum(included bins) + kk*val.
// Ties exact (final bin = exact 32-bit value). Keys register-resident.
// Last-block (ticket) finalize unchanged.
// ---------------------------------------------------------------------------
__global__ __launch_bounds__(1024)
void topk_kernel(const float* __restrict__ rank,
                 const int* __restrict__ num_pos,
                 const float2* __restrict__ blk_part,
                 unsigned long long* __restrict__ blk_topk,
                 unsigned* __restrict__ counter,
                 float* __restrict__ out) {
    int b   = blockIdx.x;
    int tid = threadIdx.x;
    int np  = num_pos[b];
    int k   = min(NEG_POS_RATIO * np, P_ - 1);

    __shared__ unsigned cnt[2048];
    __shared__ float    fsm[2048];
    __shared__ unsigned wsum[16];
    __shared__ float    wfsm[16];
    __shared__ unsigned s_pre;
    __shared__ int      s_k;
    __shared__ float    s_fhi;
    __shared__ unsigned s_ticket;
    int lane = tid & 63, wid = tid >> 6;

    double total = 0.0;
    if (k > 0) {
        const uint4* r4 = (const uint4*)(rank + (size_t)b * P_);
        unsigned key[32];
        #pragma unroll
        for (int j = 0; j < 8; ++j) {
            uint4 v = r4[j * 1024 + tid];
            key[j * 4 + 0] = v.x; key[j * 4 + 1] = v.y;
            key[j * 4 + 2] = v.z; key[j * 4 + 3] = v.w;
        }

        unsigned pre = 0;
        int kk = k;
        double fsel = 0.0;

        #pragma unroll
        for (int level = 0; level < 3; ++level) {
            const int shift = (level == 0) ? 21 : (level == 1) ? 10 : 0;
            const int hishf = (level == 1) ? 21 : 10;
            const unsigned fmask = (level == 2) ? 0x3FFu : 0x7FFu;
            const int nb = (level == 2) ? 1024 : 2048;

            cnt[tid] = 0; cnt[tid + 1024] = 0;
            fsm[tid] = 0.f; fsm[tid + 1024] = 0.f;
            __syncthreads();

            if (level == 0) {
                #pragma unroll
                for (int j = 0; j < 32; ++j) {
                    unsigned u = key[j];
                    unsigned bin = u >> 21;
                    atomicAdd(&cnt[bin], 1u);
                    atomicAdd(&fsm[bin], __uint_as_float(u));
                }
            } else {
                #pragma unroll
                for (int j = 0; j < 32; ++j) {
                    unsigned u = key[j];
                    if ((u >> hishf) == pre) {
                        unsigned bin = (u >> shift) & fmask;
                        atomicAdd(&cnt[bin], 1u);
                        atomicAdd(&fsm[bin], __uint_as_float(u));
                    }
                }
            }
            __syncthreads();

            // dual suffix scan: thread owns bins 2t, 2t+1 (zero beyond nb)
            unsigned c1 = (2 * tid + 1 < nb) ? cnt[2 * tid + 1] : 0u;
            unsigned c0 = ((2 * tid < nb) ? cnt[2 * tid] : 0u) + c1;
            float    f1 = (2 * tid + 1 < nb) ? fsm[2 * tid + 1] : 0.f;
            float    f0 = ((2 * tid < nb) ? fsm[2 * tid] : 0.f) + f1;
            unsigned g = c0, G = g;
            float    gf = f0, Gf = gf;
            #pragma unroll
            for (int off = 1; off < 64; off <<= 1) {
                unsigned r  = __shfl_down(G, off, 64);
                float    rf = __shfl_down(Gf, off, 64);
                if (lane + off < 64) { G += r; Gf += rf; }
            }
            if (lane == 0) { wsum[wid] = G; wfsm[wid] = Gf; }
            __syncthreads();
            unsigned T = 0; float Tf = 0.f;
            for (int w = wid + 1; w < 16; ++w) { T += wsum[w]; Tf += wfsm[w]; }
            unsigned A  = (G - g) + T;       // count of bins > 2t+1
            float    FA = (Gf - gf) + Tf;    // sum of bins > 2t+1
            unsigned S1 = A + c1;
            unsigned S0 = A + c0;
            unsigned ukk = (unsigned)kk;
            if (2 * tid + 1 < nb && S1 >= ukk && A < ukk) {
                s_pre = (unsigned)(2 * tid + 1); s_k = kk - (int)A; s_fhi = FA;
            } else if (2 * tid < nb && S0 >= ukk && S1 < ukk) {
                s_pre = (unsigned)(2 * tid);     s_k = kk - (int)S1; s_fhi = FA + f1;
            }
            __syncthreads();
            fsel += (double)s_fhi;
            pre = (level == 0) ? s_pre : ((pre << ((level == 2) ? 10 : 11)) | s_pre);
            kk  = s_k;
            __syncthreads();   // cnt/fsm reused next level
        }

        total = fsel + (double)kk * (double)__uint_as_float(pre);
    }

    if (tid == 0) {
        atomicExch(&blk_topk[b], (unsigned long long)__double_as_longlong(total));
        __threadfence();
        s_ticket = atomicAdd(counter, 1u);
    }
    __syncthreads();
    if (s_ticket != B_ - 1) return;

    // ----- last block: finalize -----
    __threadfence();
    double ll = 0.0, ce = 0.0;
    if (tid < MATCH_BLOCKS) {
        float2 v = blk_part[tid];
        ll = (double)v.x;
        ce = (double)v.y;
    }
    int n = (tid < B_) ? num_pos[tid] : 0;
    double tk = (tid < B_)
        ? __longlong_as_double((long long)atomicAdd(&blk_topk[tid], 0ull))
        : 0.0;

    for (int off = 32; off; off >>= 1) {
        ll += __shfl_down(ll, off, 64);
        ce += __shfl_down(ce, off, 64);
        tk += __shfl_down(tk, off, 64);
        n  += __shfl_down(n, off, 64);
    }
    __shared__ double fll[16], fce[16], ftk[16];
    __shared__ int    fn[16];
    if (lane == 0) { fll[wid] = ll; fce[wid] = ce; ftk[wid] = tk; fn[wid] = n; }
    __syncthreads();
    if (tid == 0) {
        double tll = 0.0, tce = 0.0, ttk = 0.0; int tn = 0;
        for (int i = 0; i < 16; ++i) {
            tll += fll[i]; tce += fce[i]; ttk += ftk[i]; tn += fn[i];
        }
        double Nd = (double)tn;
        out[0] = (float)(tll / Nd);
        out[1] = (float)((tce + ttk) / Nd);
    }
}

extern "C" void kernel_launch(void* const* d_in, const int* in_sizes, int n_in,
                              void* d_out, int out_size, void* d_ws, size_t ws_size,
                              hipStream_t stream) {
    const float* loc_data  = (const float*)d_in[0];
    const float* conf_data = (const float*)d_in[1];
    const float* priors    = (const float*)d_in[2];
    const float* targets   = (const float*)d_in[3];

    char* ws = (char*)d_ws;
    // layout: [bp_pack 8KB][num_pos 256B][counter 64B][blk_topk 512B @8704]
    //         [blk_part 8KB @16384][rank 8MB @65536]
    unsigned long long* bp_pack  = (unsigned long long*)ws;
    int*                num_pos  = (int*)(ws + 8192);
    unsigned*           counter  = (unsigned*)(ws + 8448);
    unsigned long long* blk_topk = (unsigned long long*)(ws + 8704);
    float2*             blk_part = (float2*)(ws + 16384);
    float*              rank     = (float*)(ws + 65536);

    hipMemsetAsync(ws, 0, 8512, stream);   // bp_pack + num_pos + counter

    best_prior_kernel<<<dim3(P_ / BP_CHUNK, B_), 256, 0, stream>>>(
        priors, targets, bp_pack);
    match_kernel<<<dim3(P_ / (512 * MCHUNK), B_), 256, 0, stream>>>(
        loc_data, conf_data, priors, targets, (const unsigned*)bp_pack,
        rank, num_pos, blk_part);
    topk_kernel<<<B_, 1024, 0, stream>>>(rank, num_pos, blk_part, blk_topk,
                                         counter, (float*)d_out);
}

// Round 17
// 82.090 us; speedup vs baseline: 1.5151x; 1.5151x over previous
//
#include <hip/hip_runtime.h>
#include <stdint.h>

#define B_ 64
#define P_ 32768
#define O_ 16
#define BP_CHUNK 1024                  // priors per block in best_prior_kernel
#define MCHUNK 4                       // sequential 256-pair chunks per match block
#define MATCH_BLOCKS (P_ / (512 * MCHUNK) * B_)   // 1024

constexpr float OVERLAP_THRESH = 0.5f;
constexpr int   NEG_POS_RATIO  = 3;
constexpr float VAR0 = 0.1f;
constexpr float VAR1 = 0.2f;

__device__ __forceinline__ unsigned long long umax64(unsigned long long a,
                                                     unsigned long long b) {
    return a > b ? a : b;
}

// ---------------------------------------------------------------------------
// Kernel 1: best prior per (b,o) = argmax_p IoU(truth o, prior p).
// Thread (g,o): scans BP_CHUNK/16 priors (stride 16) for ONE truth.
// Division-free running best; one IEEE f32 div per thread at the end (pack
// ordering must match reference rounding). Merge: shfl_xor + LDS + one
// global atomicMax per (block,o). bp_pack must be pre-zeroed.
// ---------------------------------------------------------------------------
__global__ __launch_bounds__(256)
void best_prior_kernel(const float* __restrict__ priors,
                       const float* __restrict__ targets,
                       unsigned long long* __restrict__ bp_pack) {
    int b   = blockIdx.y;
    int tid = threadIdx.x;
    int g   = tid >> 4;
    int o   = tid & 15;

    const float* t = targets + ((size_t)b * O_ + o) * 5;
    float tx0 = t[0], ty0 = t[1], tx1 = t[2], ty1 = t[3];
    float ta  = (tx1 - tx0) * (ty1 - ty0);

    int pbase = blockIdx.x * BP_CHUNK + g;
    float bin_ = 0.f, bun_ = 1.f;
    int   bp_  = pbase;

    #pragma unroll 4
    for (int j = 0; j < BP_CHUNK / 16; ++j) {
        int p = pbase + j * 16;
        float4 pr = ((const float4*)priors)[p];
        float px0 = pr.x - pr.z * 0.5f, py0 = pr.y - pr.w * 0.5f;
        float px1 = pr.x + pr.z * 0.5f, py1 = pr.y + pr.w * 0.5f;
        float pa  = (px1 - px0) * (py1 - py0);
        float w = fmaxf(fminf(tx1, px1) - fmaxf(tx0, px0), 0.f);
        float h = fmaxf(fminf(ty1, py1) - fmaxf(ty0, py0), 0.f);
        float in_ = w * h;
        float un_ = ta + pa - in_;
        bool gt = in_ * bun_ > bin_ * un_;
        bin_ = gt ? in_ : bin_;
        bun_ = gt ? un_ : bun_;
        bp_  = gt ? p   : bp_;
    }

    float iou = bin_ / bun_;
    unsigned long long pack =
        ((unsigned long long)__float_as_uint(iou) << 32) | (unsigned)(~bp_);

    pack = umax64(pack, __shfl_xor(pack, 16, 64));
    pack = umax64(pack, __shfl_xor(pack, 32, 64));

    __shared__ unsigned long long sw[4][16];
    int lane = tid & 63, wid = tid >> 6;
    if (lane < 16) sw[wid][lane] = pack;
    __syncthreads();
    if (tid < 16) {
        unsigned long long m = umax64(umax64(sw[0][tid], sw[1][tid]),
                                      umax64(sw[2][tid], sw[3][tid]));
        atomicMax(&bp_pack[(size_t)b * O_ + tid], m);
    }
}

// ---------------------------------------------------------------------------
// Kernel 2: match — R12 body (best measured: 42us, VGPR 80, the optimum of
// the fully-mapped {prefetch-depth x occupancy} space; do not add pragmas).
// ---------------------------------------------------------------------------
__device__ __forceinline__ float sl1(float d) {
    float ad = fabsf(d);
    return (ad < 1.f) ? 0.5f * d * d : ad - 0.5f;
}

__global__ __launch_bounds__(256)
void match_kernel(const float* __restrict__ loc_data,
                  const float* __restrict__ conf_data,
                  const float* __restrict__ priors,
                  const float* __restrict__ targets,
                  const unsigned* __restrict__ bp_lo,   // bp_pack viewed as u32
                  float* __restrict__ rank,
                  int* __restrict__ num_pos,
                  float2* __restrict__ blk_part) {
    int b    = blockIdx.y;
    int tid  = threadIdx.x;

    __shared__ float4 s_box[O_];    // x0,y0,x1,y1
    __shared__ float2 s_meta[O_];   // (area, bp-as-int-bits)
    if (tid < O_) {
        const float* t = targets + ((size_t)b * O_ + tid) * 5;
        float x0 = t[0], y0 = t[1], x1 = t[2], y1 = t[3];
        s_box[tid]  = make_float4(x0, y0, x1, y1);
        int bp = (int)~bp_lo[((size_t)b * O_ + tid) * 2];   // low dword (LE)
        s_meta[tid] = make_float2((x1 - x0) * (y1 - y0), __int_as_float(bp));
    }
    __syncthreads();

    float ll = 0.f, ces = 0.f;
    int   pc = 0;

    for (int c = 0; c < MCHUNK; ++c) {
        int pair = blockIdx.x * (256 * MCHUNK) + c * 256 + tid;
        int p0   = pair * 2;

        float4 prA = ((const float4*)priors)[p0];
        float4 prB = ((const float4*)priors)[p0 + 1];
        float4 cd  = ((const float4*)conf_data)[(size_t)b * (P_ / 2) + pair];

        float ax0 = prA.x - prA.z * 0.5f, ay0 = prA.y - prA.w * 0.5f;
        float ax1 = prA.x + prA.z * 0.5f, ay1 = prA.y + prA.w * 0.5f;
        float bx0 = prB.x - prB.z * 0.5f, by0 = prB.y - prB.w * 0.5f;
        float bx1 = prB.x + prB.z * 0.5f, by1 = prB.y + prB.w * 0.5f;
        float aA = (ax1 - ax0) * (ay1 - ay0);
        float aB = (bx1 - bx0) * (by1 - by0);

        float ibA = 0.f, ubA = 1.f, ibB = 0.f, ubB = 1.f;
        int miA = 0, miB = 0, fiA = -1, fiB = -1;

        #pragma unroll
        for (int o = 0; o < O_; ++o) {
            float4 tb4 = s_box[o];
            float2 mt  = s_meta[o];
            float tx0 = tb4.x, ty0 = tb4.y, tx1 = tb4.z, ty1 = tb4.w;
            float ta  = mt.x;
            int   bp  = __float_as_int(mt.y);

            float wA  = fmaxf(fminf(tx1, ax1) - fmaxf(tx0, ax0), 0.f);
            float hA  = fmaxf(fminf(ty1, ay1) - fmaxf(ty0, ay0), 0.f);
            float inA = wA * hA;
            float unA = ta + aA - inA;
            bool  gA  = inA * ubA > ibA * unA;   // strict: first index wins ties
            ibA = gA ? inA : ibA;  ubA = gA ? unA : ubA;  miA = gA ? o : miA;
            if (bp == p0) fiA = o;               // last o wins (matches reference)

            float wB  = fmaxf(fminf(tx1, bx1) - fmaxf(tx0, bx0), 0.f);
            float hB  = fmaxf(fminf(ty1, by1) - fmaxf(ty0, by0), 0.f);
            float inB = wB * hB;
            float unB = ta + aB - inB;
            bool  gB  = inB * ubB > ibB * unB;
            ibB = gB ? inB : ibB;  ubB = gB ? unB : ubB;  miB = gB ? o : miB;
            if (bp == p0 + 1) fiB = o;
        }

        bool posA = (fiA >= 0) || (2.f * ibA >= ubA);
        bool posB = (fiB >= 0) || (2.f * ibB >= ubB);

        float mA  = fmaxf(cd.x, cd.y);
        float ceA = mA + __logf(1.f + __expf(-fabsf(cd.x - cd.y))) - (posA ? cd.y : cd.x);
        float mB  = fmaxf(cd.z, cd.w);
        float ceB = mB + __logf(1.f + __expf(-fabsf(cd.z - cd.w))) - (posB ? cd.w : cd.z);

        float2 rk;
        rk.x = posA ? 0.f : ceA;
        rk.y = posB ? 0.f : ceB;
        *(float2*)(rank + (size_t)b * P_ + p0) = rk;

        if (posA) {
            int mi = (fiA >= 0) ? fiA : miA;
            float4 tb4 = s_box[mi];
            float pz = ax1 - ax0, pw = ay1 - ay0;
            float cx = (ax0 + ax1) * 0.5f, cy = (ay0 + ay1) * 0.5f;
            float gcx = __fdividef((tb4.x + tb4.z) * 0.5f - cx, VAR0 * pz);
            float gcy = __fdividef((tb4.y + tb4.w) * 0.5f - cy, VAR0 * pw);
            float gw  = __logf(__fdividef(tb4.z - tb4.x, pz)) * (1.f / VAR1);
            float gh  = __logf(__fdividef(tb4.w - tb4.y, pw)) * (1.f / VAR1);
            float4 ld = ((const float4*)loc_data)[(size_t)b * P_ + p0];
            ll  += sl1(ld.x - gcx) + sl1(ld.y - gcy) + sl1(ld.z - gw) + sl1(ld.w - gh);
            ces += ceA;
            pc  += 1;
        }
        if (posB) {
            int mi = (fiB >= 0) ? fiB : miB;
            float4 tb4 = s_box[mi];
            float pz = bx1 - bx0, pw = by1 - by0;
            float cx = (bx0 + bx1) * 0.5f, cy = (by0 + by1) * 0.5f;
            float gcx = __fdividef((tb4.x + tb4.z) * 0.5f - cx, VAR0 * pz);
            float gcy = __fdividef((tb4.y + tb4.w) * 0.5f - cy, VAR0 * pw);
            float gw  = __logf(__fdividef(tb4.z - tb4.x, pz)) * (1.f / VAR1);
            float gh  = __logf(__fdividef(tb4.w - tb4.y, pw)) * (1.f / VAR1);
            float4 ld = ((const float4*)loc_data)[(size_t)b * P_ + p0 + 1];
            ll  += sl1(ld.x - gcx) + sl1(ld.y - gcy) + sl1(ld.z - gw) + sl1(ld.w - gh);
            ces += ceB;
            pc  += 1;
        }
    }

    for (int off = 32; off; off >>= 1) {
        ll  += __shfl_down(ll, off, 64);
        ces += __shfl_down(ces, off, 64);
        pc  += __shfl_down(pc, off, 64);
    }
    __shared__ float sll[4], sce[4];
    __shared__ int   spc[4];
    int wid = tid >> 6;
    if ((tid & 63) == 0) { sll[wid] = ll; sce[wid] = ces; spc[wid] = pc; }
    __syncthreads();
    if (tid == 0) {
        int tp = spc[0] + spc[1] + spc[2] + spc[3];
        float tl = sll[0] + sll[1] + sll[2] + sll[3];
        float tc = sce[0] + sce[1] + sce[2] + sce[3];
        blk_part[blockIdx.y * gridDim.x + blockIdx.x] = make_float2(tl, tc);
        if (tp) atomicAdd(&num_pos[b], tp);
    }
}

// ---------------------------------------------------------------------------
// Kernel 3: per batch, exact top-k sum via 11/11/10-bit COUNT-ONLY radix
// select (R12-proven). Keys register-resident. NO float LDS atomics (R16:
// count+sum variant was 2.5x slower from hot-bin float-RMW serialization).
// Last-block (ticket) finalize reduces blk_part + blk_topk + num_pos -> out.
// ---------------------------------------------------------------------------
__global__ __launch_bounds__(1024)
void topk_kernel(const float* __restrict__ rank,
                 const int* __restrict__ num_pos,
                 const float2* __restrict__ blk_part,
                 unsigned long long* __restrict__ blk_topk,
                 unsigned* __restrict__ counter,
                 float* __restrict__ out) {
    int b   = blockIdx.x;
    int tid = threadIdx.x;
    int np  = num_pos[b];
    int k   = min(NEG_POS_RATIO * np, P_ - 1);

    __shared__ unsigned cnt[2048];
    __shared__ unsigned wsum[16];
    __shared__ unsigned s_pre;
    __shared__ int      s_k;
    __shared__ unsigned s_ticket;
    int lane = tid & 63, wid = tid >> 6;

    double total = 0.0;
    if (k > 0) {
        const uint4* r4 = (const uint4*)(rank + (size_t)b * P_);
        unsigned key[32];
        #pragma unroll
        for (int j = 0; j < 8; ++j) {
            uint4 v = r4[j * 1024 + tid];
            key[j * 4 + 0] = v.x; key[j * 4 + 1] = v.y;
            key[j * 4 + 2] = v.z; key[j * 4 + 3] = v.w;
        }

        unsigned pre = 0;
        int kk = k;
        #pragma unroll
        for (int level = 0; level < 3; ++level) {
            const int shift = (level == 0) ? 21 : (level == 1) ? 10 : 0;
            const int hishf = (level == 1) ? 21 : 10;
            const unsigned fmask = (level == 2) ? 0x3FFu : 0x7FFu;
            const int nb = (level == 2) ? 1024 : 2048;

            cnt[tid] = 0; cnt[tid + 1024] = 0;
            __syncthreads();

            if (level == 0) {
                #pragma unroll
                for (int j = 0; j < 32; ++j)
                    atomicAdd(&cnt[key[j] >> 21], 1u);
            } else {
                #pragma unroll
                for (int j = 0; j < 32; ++j) {
                    unsigned u = key[j];
                    if ((u >> hishf) == pre) atomicAdd(&cnt[(u >> shift) & fmask], 1u);
                }
            }
            __syncthreads();

            unsigned c1 = (2 * tid + 1 < nb) ? cnt[2 * tid + 1] : 0u;
            unsigned c0 = ((2 * tid < nb) ? cnt[2 * tid] : 0u) + c1;
            unsigned g = c0, G = g;
            #pragma unroll
            for (int off = 1; off < 64; off <<= 1) {
                unsigned r = __shfl_down(G, off, 64);
                if (lane + off < 64) G += r;
            }
            if (lane == 0) wsum[wid] = G;
            __syncthreads();
            unsigned T = 0;
            for (int w = wid + 1; w < 16; ++w) T += wsum[w];
            unsigned A  = (G - g) + T;
            unsigned S1 = A + c1;
            unsigned S0 = A + c0;
            unsigned ukk = (unsigned)kk;
            if (2 * tid + 1 < nb && S1 >= ukk && A < ukk) {
                s_pre = (unsigned)(2 * tid + 1); s_k = kk - (int)A;
            } else if (2 * tid < nb && S0 >= ukk && S1 < ukk) {
                s_pre = (unsigned)(2 * tid);     s_k = kk - (int)S1;
            }
            __syncthreads();
            pre = (pre << ((level == 2) ? 10 : 11)) | s_pre;
            kk  = s_k;
            __syncthreads();
        }

        unsigned kth = pre;
        double sum = 0.0;
        int cg = 0;
        #pragma unroll
        for (int j = 0; j < 32; ++j) {
            unsigned u = key[j];
            if (u > kth) { sum += (double)__uint_as_float(u); ++cg; }
        }
        for (int off = 32; off; off >>= 1) {
            sum += __shfl_down(sum, off, 64);
            cg  += __shfl_down(cg, off, 64);
        }
        __shared__ double ssum[16];
        __shared__ int    scg[16];
        if (lane == 0) { ssum[wid] = sum; scg[wid] = cg; }
        __syncthreads();
        if (tid == 0) {
            double tsum = 0.0; int tcg = 0;
            for (int i = 0; i < 16; ++i) { tsum += ssum[i]; tcg += scg[i]; }
            total = tsum + (double)(k - tcg) * (double)__uint_as_float(kth);
        }
    }

    if (tid == 0) {
        atomicExch(&blk_topk[b], (unsigned long long)__double_as_longlong(total));
        __threadfence();
        s_ticket = atomicAdd(counter, 1u);
    }
    __syncthreads();
    if (s_ticket != B_ - 1) return;

    // ----- last block: finalize -----
    __threadfence();
    double ll = 0.0, ce = 0.0;
    if (tid < MATCH_BLOCKS) {
        float2 v = blk_part[tid];
        ll = (double)v.x;
        ce = (double)v.y;
    }
    int n = (tid < B_) ? num_pos[tid] : 0;
    double tk = (tid < B_)
        ? __longlong_as_double((long long)atomicAdd(&blk_topk[tid], 0ull))
        : 0.0;

    for (int off = 32; off; off >>= 1) {
        ll += __shfl_down(ll, off, 64);
        ce += __shfl_down(ce, off, 64);
        tk += __shfl_down(tk, off, 64);
        n  += __shfl_down(n, off, 64);
    }
    __shared__ double fll[16], fce[16], ftk[16];
    __shared__ int    fn[16];
    if (lane == 0) { fll[wid] = ll; fce[wid] = ce; ftk[wid] = tk; fn[wid] = n; }
    __syncthreads();
    if (tid == 0) {
        double tll = 0.0, tce = 0.0, ttk = 0.0; int tn = 0;
        for (int i = 0; i < 16; ++i) {
            tll += fll[i]; tce += fce[i]; ttk += ftk[i]; tn += fn[i];
        }
        double Nd = (double)tn;
        out[0] = (float)(tll / Nd);
        out[1] = (float)((tce + ttk) / Nd);
    }
}

extern "C" void kernel_launch(void* const* d_in, const int* in_sizes, int n_in,
                              void* d_out, int out_size, void* d_ws, size_t ws_size,
                              hipStream_t stream) {
    const float* loc_data  = (const float*)d_in[0];
    const float* conf_data = (const float*)d_in[1];
    const float* priors    = (const float*)d_in[2];
    const float* targets   = (const float*)d_in[3];

    char* ws = (char*)d_ws;
    // layout: [bp_pack 8KB][num_pos 256B][counter 64B][blk_topk 512B @8704]
    //         [blk_part 8KB @16384][rank 8MB @65536]
    unsigned long long* bp_pack  = (unsigned long long*)ws;
    int*                num_pos  = (int*)(ws + 8192);
    unsigned*           counter  = (unsigned*)(ws + 8448);
    unsigned long long* blk_topk = (unsigned long long*)(ws + 8704);
    float2*             blk_part = (float2*)(ws + 16384);
    float*              rank     = (float*)(ws + 65536);

    hipMemsetAsync(ws, 0, 8512, stream);   // bp_pack + num_pos + counter

    best_prior_kernel<<<dim3(P_ / BP_CHUNK, B_), 256, 0, stream>>>(
        priors, targets, bp_pack);
    match_kernel<<<dim3(P_ / (512 * MCHUNK), B_), 256, 0, stream>>>(
        loc_data, conf_data, priors, targets, (const unsigned*)bp_pack,
        rank, num_pos, blk_part);
    topk_kernel<<<B_, 1024, 0, stream>>>(rank, num_pos, blk_part, blk_topk,
                                         counter, (float*)d_out);
}

// Round 18
// 78.057 us; speedup vs baseline: 1.5934x; 1.0517x over previous
//
#include <hip/hip_runtime.h>
#include <stdint.h>

#define B_ 64
#define P_ 32768
#define O_ 16
#define BP_CHUNK 1024                  // priors per block in best_prior_kernel
#define MCHUNK 4                       // sequential 256-pair chunks per match block
#define MATCH_BLOCKS (P_ / (512 * MCHUNK) * B_)   // 1024

constexpr float OVERLAP_THRESH = 0.5f;
constexpr int   NEG_POS_RATIO  = 3;
constexpr float VAR0 = 0.1f;
constexpr float VAR1 = 0.2f;

__device__ __forceinline__ unsigned long long umax64(unsigned long long a,
                                                     unsigned long long b) {
    return a > b ? a : b;
}

// f32 (>=0) -> 16-bit order-preserving key, round-to-nearest-even on bit 15.
__device__ __forceinline__ unsigned f32_to_key16(float f) {
    unsigned bits = __float_as_uint(f);
    return (bits + 0x7FFFu + ((bits >> 16) & 1u)) >> 16;
}

// ---------------------------------------------------------------------------
// Kernel 1: best prior per (b,o) = argmax_p IoU(truth o, prior p).
// Unchanged (R8-proven, ~7us).
// ---------------------------------------------------------------------------
__global__ __launch_bounds__(256)
void best_prior_kernel(const float* __restrict__ priors,
                       const float* __restrict__ targets,
                       unsigned long long* __restrict__ bp_pack) {
    int b   = blockIdx.y;
    int tid = threadIdx.x;
    int g   = tid >> 4;
    int o   = tid & 15;

    const float* t = targets + ((size_t)b * O_ + o) * 5;
    float tx0 = t[0], ty0 = t[1], tx1 = t[2], ty1 = t[3];
    float ta  = (tx1 - tx0) * (ty1 - ty0);

    int pbase = blockIdx.x * BP_CHUNK + g;
    float bin_ = 0.f, bun_ = 1.f;
    int   bp_  = pbase;

    #pragma unroll 4
    for (int j = 0; j < BP_CHUNK / 16; ++j) {
        int p = pbase + j * 16;
        float4 pr = ((const float4*)priors)[p];
        float px0 = pr.x - pr.z * 0.5f, py0 = pr.y - pr.w * 0.5f;
        float px1 = pr.x + pr.z * 0.5f, py1 = pr.y + pr.w * 0.5f;
        float pa  = (px1 - px0) * (py1 - py0);
        float w = fmaxf(fminf(tx1, px1) - fmaxf(tx0, px0), 0.f);
        float h = fmaxf(fminf(ty1, py1) - fmaxf(ty0, py0), 0.f);
        float in_ = w * h;
        float un_ = ta + pa - in_;
        bool gt = in_ * bun_ > bin_ * un_;
        bin_ = gt ? in_ : bin_;
        bun_ = gt ? un_ : bun_;
        bp_  = gt ? p   : bp_;
    }

    float iou = bin_ / bun_;
    unsigned long long pack =
        ((unsigned long long)__float_as_uint(iou) << 32) | (unsigned)(~bp_);

    pack = umax64(pack, __shfl_xor(pack, 16, 64));
    pack = umax64(pack, __shfl_xor(pack, 32, 64));

    __shared__ unsigned long long sw[4][16];
    int lane = tid & 63, wid = tid >> 6;
    if (lane < 16) sw[wid][lane] = pack;
    __syncthreads();
    if (tid < 16) {
        unsigned long long m = umax64(umax64(sw[0][tid], sw[1][tid]),
                                      umax64(sw[2][tid], sw[3][tid]));
        atomicMax(&bp_pack[(size_t)b * O_ + tid], m);
    }
}

// ---------------------------------------------------------------------------
// Kernel 2: match — R12 body (best measured), except rank is written as
// packed 16-bit keys (2 keys per u32): RNE top-16-bits of the f32, order-
// preserving for CE >= 0. Halves rank traffic on both sides.
// ---------------------------------------------------------------------------
__device__ __forceinline__ float sl1(float d) {
    float ad = fabsf(d);
    return (ad < 1.f) ? 0.5f * d * d : ad - 0.5f;
}

__global__ __launch_bounds__(256)
void match_kernel(const float* __restrict__ loc_data,
                  const float* __restrict__ conf_data,
                  const float* __restrict__ priors,
                  const float* __restrict__ targets,
                  const unsigned* __restrict__ bp_lo,   // bp_pack viewed as u32
                  unsigned* __restrict__ rank16,        // packed 2x u16 / u32
                  int* __restrict__ num_pos,
                  float2* __restrict__ blk_part) {
    int b    = blockIdx.y;
    int tid  = threadIdx.x;

    __shared__ float4 s_box[O_];    // x0,y0,x1,y1
    __shared__ float2 s_meta[O_];   // (area, bp-as-int-bits)
    if (tid < O_) {
        const float* t = targets + ((size_t)b * O_ + tid) * 5;
        float x0 = t[0], y0 = t[1], x1 = t[2], y1 = t[3];
        s_box[tid]  = make_float4(x0, y0, x1, y1);
        int bp = (int)~bp_lo[((size_t)b * O_ + tid) * 2];   // low dword (LE)
        s_meta[tid] = make_float2((x1 - x0) * (y1 - y0), __int_as_float(bp));
    }
    __syncthreads();

    float ll = 0.f, ces = 0.f;
    int   pc = 0;

    for (int c = 0; c < MCHUNK; ++c) {
        int pair = blockIdx.x * (256 * MCHUNK) + c * 256 + tid;
        int p0   = pair * 2;

        float4 prA = ((const float4*)priors)[p0];
        float4 prB = ((const float4*)priors)[p0 + 1];
        float4 cd  = ((const float4*)conf_data)[(size_t)b * (P_ / 2) + pair];

        float ax0 = prA.x - prA.z * 0.5f, ay0 = prA.y - prA.w * 0.5f;
        float ax1 = prA.x + prA.z * 0.5f, ay1 = prA.y + prA.w * 0.5f;
        float bx0 = prB.x - prB.z * 0.5f, by0 = prB.y - prB.w * 0.5f;
        float bx1 = prB.x + prB.z * 0.5f, by1 = prB.y + prB.w * 0.5f;
        float aA = (ax1 - ax0) * (ay1 - ay0);
        float aB = (bx1 - bx0) * (by1 - by0);

        float ibA = 0.f, ubA = 1.f, ibB = 0.f, ubB = 1.f;
        int miA = 0, miB = 0, fiA = -1, fiB = -1;

        #pragma unroll
        for (int o = 0; o < O_; ++o) {
            float4 tb4 = s_box[o];
            float2 mt  = s_meta[o];
            float tx0 = tb4.x, ty0 = tb4.y, tx1 = tb4.z, ty1 = tb4.w;
            float ta  = mt.x;
            int   bp  = __float_as_int(mt.y);

            float wA  = fmaxf(fminf(tx1, ax1) - fmaxf(tx0, ax0), 0.f);
            float hA  = fmaxf(fminf(ty1, ay1) - fmaxf(ty0, ay0), 0.f);
            float inA = wA * hA;
            float unA = ta + aA - inA;
            bool  gA  = inA * ubA > ibA * unA;   // strict: first index wins ties
            ibA = gA ? inA : ibA;  ubA = gA ? unA : ubA;  miA = gA ? o : miA;
            if (bp == p0) fiA = o;               // last o wins (matches reference)

            float wB  = fmaxf(fminf(tx1, bx1) - fmaxf(tx0, bx0), 0.f);
            float hB  = fmaxf(fminf(ty1, by1) - fmaxf(ty0, by0), 0.f);
            float inB = wB * hB;
            float unB = ta + aB - inB;
            bool  gB  = inB * ubB > ibB * unB;
            ibB = gB ? inB : ibB;  ubB = gB ? unB : ubB;  miB = gB ? o : miB;
            if (bp == p0 + 1) fiB = o;
        }

        bool posA = (fiA >= 0) || (2.f * ibA >= ubA);
        bool posB = (fiB >= 0) || (2.f * ibB >= ubB);

        float mA  = fmaxf(cd.x, cd.y);
        float ceA = mA + __logf(1.f + __expf(-fabsf(cd.x - cd.y))) - (posA ? cd.y : cd.x);
        float mB  = fmaxf(cd.z, cd.w);
        float ceB = mB + __logf(1.f + __expf(-fabsf(cd.z - cd.w))) - (posB ? cd.w : cd.z);

        unsigned kA = posA ? 0u : f32_to_key16(ceA);
        unsigned kB = posB ? 0u : f32_to_key16(ceB);
        rank16[((size_t)b * P_ + p0) >> 1] = kA | (kB << 16);

        if (posA) {
            int mi = (fiA >= 0) ? fiA : miA;
            float4 tb4 = s_box[mi];
            float pz = ax1 - ax0, pw = ay1 - ay0;
            float cx = (ax0 + ax1) * 0.5f, cy = (ay0 + ay1) * 0.5f;
            float gcx = __fdividef((tb4.x + tb4.z) * 0.5f - cx, VAR0 * pz);
            float gcy = __fdividef((tb4.y + tb4.w) * 0.5f - cy, VAR0 * pw);
            float gw  = __logf(__fdividef(tb4.z - tb4.x, pz)) * (1.f / VAR1);
            float gh  = __logf(__fdividef(tb4.w - tb4.y, pw)) * (1.f / VAR1);
            float4 ld = ((const float4*)loc_data)[(size_t)b * P_ + p0];
            ll  += sl1(ld.x - gcx) + sl1(ld.y - gcy) + sl1(ld.z - gw) + sl1(ld.w - gh);
            ces += ceA;
            pc  += 1;
        }
        if (posB) {
            int mi = (fiB >= 0) ? fiB : miB;
            float4 tb4 = s_box[mi];
            float pz = bx1 - bx0, pw = by1 - by0;
            float cx = (bx0 + bx1) * 0.5f, cy = (by0 + by1) * 0.5f;
            float gcx = __fdividef((tb4.x + tb4.z) * 0.5f - cx, VAR0 * pz);
            float gcy = __fdividef((tb4.y + tb4.w) * 0.5f - cy, VAR0 * pw);
            float gw  = __logf(__fdividef(tb4.z - tb4.x, pz)) * (1.f / VAR1);
            float gh  = __logf(__fdividef(tb4.w - tb4.y, pw)) * (1.f / VAR1);
            float4 ld = ((const float4*)loc_data)[(size_t)b * P_ + p0 + 1];
            ll  += sl1(ld.x - gcx) + sl1(ld.y - gcy) + sl1(ld.z - gw) + sl1(ld.w - gh);
            ces += ceB;
            pc  += 1;
        }
    }

    for (int off = 32; off; off >>= 1) {
        ll  += __shfl_down(ll, off, 64);
        ces += __shfl_down(ces, off, 64);
        pc  += __shfl_down(pc, off, 64);
    }
    __shared__ float sll[4], sce[4];
    __shared__ int   spc[4];
    int wid = tid >> 6;
    if ((tid & 63) == 0) { sll[wid] = ll; sce[wid] = ces; spc[wid] = pc; }
    __syncthreads();
    if (tid == 0) {
        int tp = spc[0] + spc[1] + spc[2] + spc[3];
        float tl = sll[0] + sll[1] + sll[2] + sll[3];
        float tc = sce[0] + sce[1] + sce[2] + sce[3];
        blk_part[blockIdx.y * gridDim.x + blockIdx.x] = make_float2(tl, tc);
        if (tp) atomicAdd(&num_pos[b], tp);
    }
}

// ---------------------------------------------------------------------------
// Kernel 3: per batch, top-k sum over 16-bit keys via 11/5-bit radix select
// (2 levels). Keys register-resident as 4x uint4 (8 keys each, 64KB/batch).
// top-k sum = sum(key > kth) + (k - cg) * val(kth)  (tie-exact on keys).
// val(key) = f32(key << 16); RNE rounding keeps sum error ~1e-3 << 0.17.
// Last-block (ticket) finalize reduces blk_part + blk_topk + num_pos -> out.
// ---------------------------------------------------------------------------
__global__ __launch_bounds__(1024)
void topk_kernel(const unsigned* __restrict__ rank16,
                 const int* __restrict__ num_pos,
                 const float2* __restrict__ blk_part,
                 unsigned long long* __restrict__ blk_topk,
                 unsigned* __restrict__ counter,
                 float* __restrict__ out) {
    int b   = blockIdx.x;
    int tid = threadIdx.x;
    int np  = num_pos[b];
    int k   = min(NEG_POS_RATIO * np, P_ - 1);

    __shared__ unsigned cnt[2048];
    __shared__ unsigned wsum[16];
    __shared__ unsigned s_pre;
    __shared__ int      s_k;
    __shared__ unsigned s_ticket;
    int lane = tid & 63, wid = tid >> 6;

    double total = 0.0;
    if (k > 0) {
        const uint4* r4 = (const uint4*)(rank16 + (size_t)b * (P_ / 2));
        uint4 kv[4];
        #pragma unroll
        for (int j = 0; j < 4; ++j) kv[j] = r4[j * 1024 + tid];

        unsigned pre = 0;
        int kk = k;
        #pragma unroll
        for (int level = 0; level < 2; ++level) {
            const int nb = (level == 0) ? 2048 : 32;

            cnt[tid] = 0; cnt[tid + 1024] = 0;
            __syncthreads();

            #pragma unroll
            for (int j = 0; j < 4; ++j) {
                unsigned d[4] = {kv[j].x, kv[j].y, kv[j].z, kv[j].w};
                #pragma unroll
                for (int q = 0; q < 4; ++q) {
                    unsigned lo = d[q] & 0xFFFFu;
                    unsigned hi = d[q] >> 16;
                    if (level == 0) {
                        atomicAdd(&cnt[lo >> 5], 1u);
                        atomicAdd(&cnt[hi >> 5], 1u);
                    } else {
                        if ((lo >> 5) == pre) atomicAdd(&cnt[lo & 31u], 1u);
                        if ((hi >> 5) == pre) atomicAdd(&cnt[hi & 31u], 1u);
                    }
                }
            }
            __syncthreads();

            unsigned c1 = (2 * tid + 1 < nb) ? cnt[2 * tid + 1] : 0u;
            unsigned c0 = ((2 * tid < nb) ? cnt[2 * tid] : 0u) + c1;
            unsigned g = c0, G = g;
            #pragma unroll
            for (int off = 1; off < 64; off <<= 1) {
                unsigned r = __shfl_down(G, off, 64);
                if (lane + off < 64) G += r;
            }
            if (lane == 0) wsum[wid] = G;
            __syncthreads();
            unsigned T = 0;
            for (int w = wid + 1; w < 16; ++w) T += wsum[w];
            unsigned A  = (G - g) + T;
            unsigned S1 = A + c1;
            unsigned S0 = A + c0;
            unsigned ukk = (unsigned)kk;
            if (2 * tid + 1 < nb && S1 >= ukk && A < ukk) {
                s_pre = (unsigned)(2 * tid + 1); s_k = kk - (int)A;
            } else if (2 * tid < nb && S0 >= ukk && S1 < ukk) {
                s_pre = (unsigned)(2 * tid);     s_k = kk - (int)S1;
            }
            __syncthreads();
            pre = (level == 0) ? s_pre : ((pre << 5) | s_pre);
            kk  = s_k;
            __syncthreads();
        }

        unsigned kth = pre;   // 16-bit key of the k-th largest
        double sum = 0.0;
        int cg = 0;
        #pragma unroll
        for (int j = 0; j < 4; ++j) {
            unsigned d[4] = {kv[j].x, kv[j].y, kv[j].z, kv[j].w};
            #pragma unroll
            for (int q = 0; q < 4; ++q) {
                unsigned lo = d[q] & 0xFFFFu;
                unsigned hi = d[q] >> 16;
                if (lo > kth) { sum += (double)__uint_as_float(lo << 16); ++cg; }
                if (hi > kth) { sum += (double)__uint_as_float(hi << 16); ++cg; }
            }
        }
        for (int off = 32; off; off >>= 1) {
            sum += __shfl_down(sum, off, 64);
            cg  += __shfl_down(cg, off, 64);
        }
        __shared__ double ssum[16];
        __shared__ int    scg[16];
        if (lane == 0) { ssum[wid] = sum; scg[wid] = cg; }
        __syncthreads();
        if (tid == 0) {
            double tsum = 0.0; int tcg = 0;
            for (int i = 0; i < 16; ++i) { tsum += ssum[i]; tcg += scg[i]; }
            total = tsum + (double)(k - tcg) * (double)__uint_as_float(kth << 16);
        }
    }

    if (tid == 0) {
        atomicExch(&blk_topk[b], (unsigned long long)__double_as_longlong(total));
        __threadfence();
        s_ticket = atomicAdd(counter, 1u);
    }
    __syncthreads();
    if (s_ticket != B_ - 1) return;

    // ----- last block: finalize -----
    __threadfence();
    double ll = 0.0, ce = 0.0;
    if (tid < MATCH_BLOCKS) {
        float2 v = blk_part[tid];
        ll = (double)v.x;
        ce = (double)v.y;
    }
    int n = (tid < B_) ? num_pos[tid] : 0;
    double tk = (tid < B_)
        ? __longlong_as_double((long long)atomicAdd(&blk_topk[tid], 0ull))
        : 0.0;

    for (int off = 32; off; off >>= 1) {
        ll += __shfl_down(ll, off, 64);
        ce += __shfl_down(ce, off, 64);
        tk += __shfl_down(tk, off, 64);
        n  += __shfl_down(n, off, 64);
    }
    __shared__ double fll[16], fce[16], ftk[16];
    __shared__ int    fn[16];
    if (lane == 0) { fll[wid] = ll; fce[wid] = ce; ftk[wid] = tk; fn[wid] = n; }
    __syncthreads();
    if (tid == 0) {
        double tll = 0.0, tce = 0.0, ttk = 0.0; int tn = 0;
        for (int i = 0; i < 16; ++i) {
            tll += fll[i]; tce += fce[i]; ttk += ftk[i]; tn += fn[i];
        }
        double Nd = (double)tn;
        out[0] = (float)(tll / Nd);
        out[1] = (float)((tce + ttk) / Nd);
    }
}

extern "C" void kernel_launch(void* const* d_in, const int* in_sizes, int n_in,
                              void* d_out, int out_size, void* d_ws, size_t ws_size,
                              hipStream_t stream) {
    const float* loc_data  = (const float*)d_in[0];
    const float* conf_data = (const float*)d_in[1];
    const float* priors    = (const float*)d_in[2];
    const float* targets   = (const float*)d_in[3];

    char* ws = (char*)d_ws;
    // layout: [bp_pack 8KB][num_pos 256B][counter 64B][blk_topk 512B @8704]
    //         [blk_part 8KB @16384][rank16 4MB @65536]
    unsigned long long* bp_pack  = (unsigned long long*)ws;
    int*                num_pos  = (int*)(ws + 8192);
    unsigned*           counter  = (unsigned*)(ws + 8448);
    unsigned long long* blk_topk = (unsigned long long*)(ws + 8704);
    float2*             blk_part = (float2*)(ws + 16384);
    unsigned*           rank16   = (unsigned*)(ws + 65536);

    hipMemsetAsync(ws, 0, 8512, stream);   // bp_pack + num_pos + counter

    best_prior_kernel<<<dim3(P_ / BP_CHUNK, B_), 256, 0, stream>>>(
        priors, targets, bp_pack);
    match_kernel<<<dim3(P_ / (512 * MCHUNK), B_), 256, 0, stream>>>(
        loc_data, conf_data, priors, targets, (const unsigned*)bp_pack,
        rank16, num_pos, blk_part);
    topk_kernel<<<B_, 1024, 0, stream>>>(rank16, num_pos, blk_part, blk_topk,
                                         counter, (float*)d_out);
}